// Round 5
// baseline (667.659 us; speedup 1.0000x reference)
//
#include <hip/hip_runtime.h>
#include <hip/hip_bf16.h>
#include <stdint.h>

#define BB 4
#define SQL 2048
#define SKL 2048
#define EMB 1024
#define NH 16
#define DH 64

typedef __bf16 bf16x8 __attribute__((ext_vector_type(8)));
typedef short s16x4 __attribute__((ext_vector_type(4)));
typedef float f32x4 __attribute__((ext_vector_type(4)));

// scale folded into Q projection: 1/sqrt(64) * log2(e)
#define QSCALE 0.1803368801111144f

__device__ __forceinline__ unsigned short f2bf(float f) {
  union { float f; uint32_t u; } v; v.f = f;
  uint32_t u = v.u;
  return (unsigned short)((u + 0x7fffu + ((u >> 16) & 1u)) >> 16);
}

typedef const __attribute__((address_space(1))) void* gas_t;
typedef __attribute__((address_space(3))) void* las_t;
__device__ __forceinline__ void gld16(const void* g, void* l) {
  __builtin_amdgcn_global_load_lds((gas_t)g, (las_t)l, 16, 0, 0);
}

// ---------------- fp32 -> bf16 convert ----------------
__global__ void cvt_bf16_kernel(const float* __restrict__ src,
                                unsigned short* __restrict__ dst, int n4) {
  int i = blockIdx.x * 256 + threadIdx.x;
  if (i >= n4) return;
  float4 v = ((const float4*)src)[i];
  ushort4 o;
  o.x = f2bf(v.x); o.y = f2bf(v.y); o.z = f2bf(v.z); o.w = f2bf(v.w);
  ((ushort4*)dst)[i] = o;
}

// ---------------- w [K][N] fp32 -> w^T [N][K] bf16 ----------------
__global__ void wtrans_kernel(const float* __restrict__ w0, const float* __restrict__ w1,
                              const float* __restrict__ w2,
                              unsigned short* __restrict__ o0, unsigned short* __restrict__ o1,
                              unsigned short* __restrict__ o2) {
  __shared__ float t[32][33];
  const float* w = blockIdx.z == 0 ? w0 : (blockIdx.z == 1 ? w1 : w2);
  unsigned short* o = blockIdx.z == 0 ? o0 : (blockIdx.z == 1 ? o1 : o2);
  int tx = threadIdx.x & 31, ty = threadIdx.x >> 5;
  int n0 = blockIdx.x * 32, k0 = blockIdx.y * 32;
#pragma unroll
  for (int r = 0; r < 4; r++)
    t[ty + r * 8][tx] = w[(size_t)(k0 + ty + r * 8) * EMB + n0 + tx];
  __syncthreads();
#pragma unroll
  for (int r = 0; r < 4; r++)
    o[(size_t)(n0 + ty + r * 8) * EMB + k0 + tx] = f2bf(t[tx][ty + r * 8]);
}

// ---------------- mask int32 -> packed halfword AND-masks ----------------
// out word w = masks for kv=2w (low half) and kv=2w+1 (high half); mask true -> 0x0000
__global__ void maskf_kernel(const int* __restrict__ m, unsigned int* __restrict__ w) {
  int t = blockIdx.x * 256 + threadIdx.x;
  const int4* p = (const int4*)(m + (size_t)t * 32);
  unsigned int* dst = w + (size_t)t * 16;
#pragma unroll
  for (int j = 0; j < 8; j++) {
    int4 v = p[j];
    unsigned int w0 = (v.x ? 0u : 0xffffu) | (v.y ? 0u : 0xffff0000u);
    unsigned int w1 = (v.z ? 0u : 0xffffu) | (v.w ? 0u : 0xffff0000u);
    dst[j * 2] = w0;
    dst[j * 2 + 1] = w1;
  }
}

// ---------------- fused projection GEMMs (z = 0:Q, 1:K, 2:V) ----------------
// z 0/1: out[bh][s][64] bf16 (Q pre-scaled by QSCALE).
// z 2:   out in per-64kv-chunk MFMA-fragment-major order (see attn_kernel).
__global__ __launch_bounds__(256, 2) void proj_gemm_kernel(
    const unsigned short* __restrict__ Aq, const unsigned short* __restrict__ Akv,
    const unsigned short* __restrict__ W0, const unsigned short* __restrict__ W1,
    const unsigned short* __restrict__ W2,
    const float* __restrict__ bq, const float* __restrict__ bk, const float* __restrict__ bv,
    unsigned short* __restrict__ Oq, unsigned short* __restrict__ Ok,
    unsigned short* __restrict__ Ov) {
  __shared__ short As[128 * 32];
  __shared__ short Bs[128 * 32];
  const int z = blockIdx.z;
  const unsigned short* A = (z == 0) ? Aq : Akv;
  const unsigned short* Bt = (z == 0) ? W0 : (z == 1 ? W1 : W2);
  const float* bias = (z == 0) ? bq : (z == 1 ? bk : bv);
  unsigned short* out = (z == 0) ? Oq : (z == 1 ? Ok : Ov);
  const float oscale = (z == 0) ? QSCALE : 1.0f;

  const int tid = threadIdx.x;
  const int wave = tid >> 6, lane = tid & 63;
  const int l15 = lane & 15, q4 = lane >> 4;
  const int wm = wave >> 1, wn = wave & 1;
  const int m0 = blockIdx.y * 128, n0 = blockIdx.x * 128;

  f32x4 acc[4][4];
#pragma unroll
  for (int i = 0; i < 4; i++)
#pragma unroll
    for (int j = 0; j < 4; j++) acc[i][j] = (f32x4){0.f, 0.f, 0.f, 0.f};

  const int r = tid >> 2;
  const int c = (tid & 3) * 8;
  const unsigned short* gA0 = A + (size_t)(m0 + r) * EMB + c;
  const unsigned short* gA1 = A + (size_t)(m0 + r + 64) * EMB + c;
  const unsigned short* gB0 = Bt + (size_t)(n0 + r) * EMB + c;
  const unsigned short* gB1 = Bt + (size_t)(n0 + r + 64) * EMB + c;
  short* lA0 = As + tid * 8;
  short* lA1 = As + tid * 8 + 2048;
  short* lB0 = Bs + tid * 8;
  short* lB1 = Bs + tid * 8 + 2048;

  for (int kt = 0; kt < EMB / 32; kt++) {
    __syncthreads();
    gld16(gA0 + kt * 32, lA0);
    gld16(gA1 + kt * 32, lA1);
    gld16(gB0 + kt * 32, lB0);
    gld16(gB1 + kt * 32, lB1);
    __syncthreads();
    bf16x8 a[4], b[4];
#pragma unroll
    for (int i = 0; i < 4; i++)
      a[i] = *(const bf16x8*)(As + (wm * 64 + i * 16 + l15) * 32 + q4 * 8);
#pragma unroll
    for (int j = 0; j < 4; j++)
      b[j] = *(const bf16x8*)(Bs + (wn * 64 + j * 16 + l15) * 32 + q4 * 8);
#pragma unroll
    for (int i = 0; i < 4; i++)
#pragma unroll
      for (int j = 0; j < 4; j++)
        acc[i][j] = __builtin_amdgcn_mfma_f32_16x16x32_bf16(a[i], b[j], acc[i][j], 0, 0, 0);
  }

#pragma unroll
  for (int i = 0; i < 4; i++) {
    const int mrow = m0 + wm * 64 + i * 16 + q4 * 4;
#pragma unroll
    for (int j = 0; j < 4; j++) {
      const int n = n0 + wn * 64 + j * 16 + l15;
      const float bvv = bias[n];
      const int h = n >> 6, d = n & 63;
      if (z <= 1) {
#pragma unroll
        for (int rg = 0; rg < 4; rg++) {
          int m = mrow + rg;
          int bb = m >> 11, sq = m & 2047;
          out[(size_t)((bb * NH + h) * SQL + sq) * DH + d] = f2bf((acc[i][j][rg] + bvv) * oscale);
        }
      } else {
        // fragment-major V: chunk=64 kv, frag F=sub*4+dsub, lane=q4v*16+l15v, j=kv&3
        int bb = mrow >> 11, sq = mrow & 2047;
        int chunk = sq >> 6, r64 = sq & 63;
        int sub = r64 >> 4, q4v = (r64 >> 2) & 3;
        int dsub = d >> 4, l15v = d & 15;
        int slot = ((sub * 4 + dsub) << 6) + q4v * 16 + l15v;
        ushort4 pk;
        pk.x = f2bf(acc[i][j][0] + bvv);
        pk.y = f2bf(acc[i][j][1] + bvv);
        pk.z = f2bf(acc[i][j][2] + bvv);
        pk.w = f2bf(acc[i][j][3] + bvv);
        *(ushort4*)(out + (size_t)(bb * NH + h) * (SKL * DH) + chunk * 4096 + slot * 4) = pk;
      }
    }
  }
}

// ---------------- fused flash attention v3 (dbuf fix) ----------------
// grid (32 qtiles, 64 bh), 256 threads; wave handles 16 q rows.
// S^T = K.Q^T (C: kv=q4*4+rg, q=l15) feeds PV 16x16x16 A-frag directly.
// K frags: direct 16B global loads. V: fragment-major LDS, conflict-free b64 reads.
// Mask: halfword AND on packed bf16 P. Row-sum: ones-MFMA.
__global__ __launch_bounds__(256, 4) void attn_kernel(
    const unsigned short* __restrict__ Qb,  // [64][2048][64] bf16 (pre-scaled)
    const unsigned short* __restrict__ Kb,  // [64][2048][64]
    const unsigned short* __restrict__ Vg,  // [64][32 chunks][4096] frag-major
    const unsigned int* __restrict__ mw,    // [4][2048][1024] halfword AND-masks
    float* __restrict__ out) {              // [4][2048][1024]
  __shared__ short Vs[2 * 4096];  // double-buffered 8KB chunks
  const int tid = threadIdx.x;
  const int wave = tid >> 6, lane = tid & 63;
  const int l15 = lane & 15, q4 = lane >> 4;
  const int bh = blockIdx.y, b = bh >> 4, h = bh & 15;
  const int q0 = blockIdx.x * 64 + wave * 16;

  // Q b-frag (n=q=l15, k=d=q4*8+j)
  const unsigned short* qg = Qb + (size_t)(bh * SQL + q0 + l15) * DH + q4 * 8;
  const bf16x8 qa0 = *(const bf16x8*)qg;
  const bf16x8 qa1 = *(const bf16x8*)(qg + 32);

  f32x4 o[4];
#pragma unroll
  for (int j = 0; j < 4; j++) o[j] = (f32x4){0.f, 0.f, 0.f, 0.f};
  f32x4 osum = (f32x4){0.f, 0.f, 0.f, 0.f};
  const s16x4 ones = (s16x4){0x3f80, 0x3f80, 0x3f80, 0x3f80};

  const unsigned short* vgb = Vg + (size_t)bh * (SKL * DH);
  const unsigned short* kcb = Kb + (size_t)bh * (SKL * DH) + (size_t)(l15)*64 + q4 * 8;
  const unsigned int* mrp = mw + ((size_t)b * SQL + q0 + l15) * 1024 + q4 * 2;

  // stage chunk 0
  gld16(vgb + tid * 8, Vs + tid * 8);
  gld16(vgb + 2048 + tid * 8, Vs + 2048 + tid * 8);
  __syncthreads();

  for (int cch = 0; cch < 32; cch++) {
    const int buf = cch & 1;
    if (cch < 31) {  // prefetch next chunk (overlapped with compute below)
      const unsigned short* src = vgb + (size_t)(cch + 1) * 4096 + tid * 8;
      short* dst = Vs + (buf ^ 1) * 4096 + tid * 8;
      gld16(src, dst);
      gld16(src + 2048, dst + 2048);
    }

    const unsigned short* kc = kcb + (size_t)cch * 4096;
    const short* vlane = Vs + buf * 4096 + lane * 4;  // FIX: read from current buffer
    const unsigned int* mc = mrp + cch * 32;

#pragma unroll
    for (int sub = 0; sub < 4; sub++) {
      const unsigned short* kr = kc + sub * 1024;
      bf16x8 af0 = *(const bf16x8*)kr;
      bf16x8 af1 = *(const bf16x8*)(kr + 32);
      f32x4 s4 = (f32x4){0.f, 0.f, 0.f, 0.f};
      s4 = __builtin_amdgcn_mfma_f32_16x16x32_bf16(af0, qa0, s4, 0, 0, 0);
      s4 = __builtin_amdgcn_mfma_f32_16x16x32_bf16(af1, qa1, s4, 0, 0, 0);

      uint2 mk = *(const uint2*)(mc + sub * 8);
      union { float f; uint32_t u; } e0, e1, e2, e3;
      e0.f = __builtin_exp2f(s4[0]);
      e1.f = __builtin_exp2f(s4[1]);
      e2.f = __builtin_exp2f(s4[2]);
      e3.f = __builtin_exp2f(s4[3]);
      uint32_t lo = (((e0.u + 0x8000u) >> 16) | ((e1.u + 0x8000u) & 0xffff0000u)) & mk.x;
      uint32_t hi = (((e2.u + 0x8000u) >> 16) | ((e3.u + 0x8000u) & 0xffff0000u)) & mk.y;
      uint2 ppu; ppu.x = lo; ppu.y = hi;
      s16x4 pp = __builtin_bit_cast(s16x4, ppu);

      const short* vf = vlane + sub * 1024;  // frag F=sub*4+dsub at offset F*256 shorts
      o[0] = __builtin_amdgcn_mfma_f32_16x16x16bf16_1k(pp, *(const s16x4*)(vf + 0), o[0], 0, 0, 0);
      o[1] = __builtin_amdgcn_mfma_f32_16x16x16bf16_1k(pp, *(const s16x4*)(vf + 256), o[1], 0, 0, 0);
      o[2] = __builtin_amdgcn_mfma_f32_16x16x16bf16_1k(pp, *(const s16x4*)(vf + 512), o[2], 0, 0, 0);
      o[3] = __builtin_amdgcn_mfma_f32_16x16x16bf16_1k(pp, *(const s16x4*)(vf + 768), o[3], 0, 0, 0);
      osum = __builtin_amdgcn_mfma_f32_16x16x16bf16_1k(pp, ones, osum, 0, 0, 0);
    }
    __syncthreads();
  }

#pragma unroll
  for (int rg = 0; rg < 4; rg++) {
    const float inv = 1.0f / osum[rg];
    float* op = out + (size_t)(b * SQL + q0 + q4 * 4 + rg) * 1024 + h * DH + l15;
#pragma unroll
    for (int dsub = 0; dsub < 4; dsub++) op[dsub * 16] = o[dsub][rg] * inv;
  }
}

extern "C" void kernel_launch(void* const* d_in, const int* in_sizes, int n_in,
                              void* d_out, int out_size, void* d_ws, size_t ws_size,
                              hipStream_t stream) {
  const float* x_q  = (const float*)d_in[0];
  const float* x_kv = (const float*)d_in[1];
  const int*   amask = (const int*)d_in[2];
  const float* w_q  = (const float*)d_in[3];
  const float* b_q  = (const float*)d_in[4];
  const float* w_k  = (const float*)d_in[5];
  const float* b_k  = (const float*)d_in[6];
  const float* w_v  = (const float*)d_in[7];
  const float* b_v  = (const float*)d_in[8];
  float* out = (float*)d_out;

  char* ws = (char*)d_ws;
  // Phase 1 (dead after proj): xq/xkv/w at [0, 38MB)
  unsigned short* xq_bf  = (unsigned short*)(ws + 0);          // 16 MB
  unsigned short* xkv_bf = (unsigned short*)(ws + 16777216);   // 16 MB
  unsigned short* wqt    = (unsigned short*)(ws + 33554432);   // 2 MB
  unsigned short* wkt    = (unsigned short*)(ws + 35651584);   // 2 MB
  unsigned short* wvt    = (unsigned short*)(ws + 37748736);   // 2 MB
  // Phase 2 (live into attn)
  unsigned short* Qb     = (unsigned short*)(ws + 39845888);   // 16 MB
  unsigned short* Kb     = (unsigned short*)(ws + 56623104);   // 16 MB
  unsigned short* Vgb    = (unsigned short*)(ws + 73400320);   // 16 MB
  // M32 written AFTER proj, overlaying the dead phase-1 region [0, 32MB)
  unsigned int*   M32    = (unsigned int*)(ws + 0);            // 32 MB

  cvt_bf16_kernel<<<8192, 256, 0, stream>>>(x_q, xq_bf, 2097152);
  cvt_bf16_kernel<<<8192, 256, 0, stream>>>(x_kv, xkv_bf, 2097152);
  wtrans_kernel<<<dim3(32, 32, 3), 256, 0, stream>>>(w_q, w_k, w_v, wqt, wkt, wvt);
  proj_gemm_kernel<<<dim3(8, 64, 3), 256, 0, stream>>>(
      xq_bf, xkv_bf, wqt, wkt, wvt, b_q, b_k, b_v, Qb, Kb, Vgb);
  maskf_kernel<<<2048, 256, 0, stream>>>(amask, M32);
  attn_kernel<<<dim3(32, 64), 256, 0, stream>>>(Qb, Kb, Vgb, M32, out);
}

// Round 6
// 386.714 us; speedup vs baseline: 1.7265x; 1.7265x over previous
//
#include <hip/hip_runtime.h>
#include <hip/hip_bf16.h>
#include <stdint.h>

#define BB 4
#define SQL 2048
#define SKL 2048
#define EMB 1024
#define NH 16
#define DH 64

typedef __bf16 bf16x8 __attribute__((ext_vector_type(8)));
typedef float f32x4 __attribute__((ext_vector_type(4)));

// scale folded into Q projection: 1/sqrt(64) * log2(e)
#define QSCALE 0.1803368801111144f

__device__ __forceinline__ unsigned short f2bf(float f) {
  union { float f; uint32_t u; } v; v.f = f;
  uint32_t u = v.u;
  return (unsigned short)((u + 0x7fffu + ((u >> 16) & 1u)) >> 16);
}

typedef const __attribute__((address_space(1))) void* gas_t;
typedef __attribute__((address_space(3))) void* las_t;
__device__ __forceinline__ void gld16(const void* g, void* l) {
  __builtin_amdgcn_global_load_lds((gas_t)g, (las_t)l, 16, 0, 0);
}

// ---------------- fp32 -> bf16 convert ----------------
__global__ void cvt_bf16_kernel(const float* __restrict__ src,
                                unsigned short* __restrict__ dst, int n4) {
  int i = blockIdx.x * 256 + threadIdx.x;
  if (i >= n4) return;
  float4 v = ((const float4*)src)[i];
  ushort4 o;
  o.x = f2bf(v.x); o.y = f2bf(v.y); o.z = f2bf(v.z); o.w = f2bf(v.w);
  ((ushort4*)dst)[i] = o;
}

// ---------------- w [K][N] fp32 -> w^T [N][K] bf16 ----------------
__global__ void wtrans_kernel(const float* __restrict__ w0, const float* __restrict__ w1,
                              const float* __restrict__ w2,
                              unsigned short* __restrict__ o0, unsigned short* __restrict__ o1,
                              unsigned short* __restrict__ o2) {
  __shared__ float t[32][33];
  const float* w = blockIdx.z == 0 ? w0 : (blockIdx.z == 1 ? w1 : w2);
  unsigned short* o = blockIdx.z == 0 ? o0 : (blockIdx.z == 1 ? o1 : o2);
  int tx = threadIdx.x & 31, ty = threadIdx.x >> 5;
  int n0 = blockIdx.x * 32, k0 = blockIdx.y * 32;
#pragma unroll
  for (int r = 0; r < 4; r++)
    t[ty + r * 8][tx] = w[(size_t)(k0 + ty + r * 8) * EMB + n0 + tx];
  __syncthreads();
#pragma unroll
  for (int r = 0; r < 4; r++)
    o[(size_t)(n0 + ty + r * 8) * EMB + k0 + tx] = f2bf(t[tx][ty + r * 8]);
}

// ---------------- mask -> permuted halfword AND-masks ----------------
// Layout: [row=b*2048+sq][chunk(32)][32 words]; word idx = q4*8 + sub*2 + pair
// holds kv = chunk*64 + sub*16 + q4*4 + pair*2 (lo) / +1 (hi); true -> 0x0000.
__global__ void maskf_kernel(const int* __restrict__ m, unsigned int* __restrict__ w) {
  int t = blockIdx.x * 256 + threadIdx.x;  // 262144: row*32+chunk
  int row = t >> 5, chunk = t & 31;
  const int* src = m + (size_t)row * 2048 + chunk * 64;
  int v[64];
#pragma unroll
  for (int j = 0; j < 16; j++) {
    int4 x = ((const int4*)src)[j];
    v[j * 4] = x.x; v[j * 4 + 1] = x.y; v[j * 4 + 2] = x.z; v[j * 4 + 3] = x.w;
  }
  unsigned int* dst = w + (size_t)t * 32;
#pragma unroll
  for (int idx = 0; idx < 32; idx++) {
    int q4 = idx >> 3, sub = (idx >> 1) & 3, pair = idx & 1;
    int kv = sub * 16 + q4 * 4 + pair * 2;
    dst[idx] = (v[kv] ? 0u : 0xffffu) | (v[kv + 1] ? 0u : 0xffff0000u);
  }
}

// ---------------- fused projection GEMMs (z = 0:Q, 1:K, 2:V) ----------------
// z 0: out[bh][s][64] bf16, pre-scaled by QSCALE.
// z 1: K fragment-major: [bh][chunk][ (sub*2+half_d)*512 + (q4k*16+kv16)*8 + jk ]
//      value K(kv=chunk*64+sub*16+kv16, d=half_d*32+q4k*8+jk)  (QK^T A-frag order)
// z 2: V fragment-major: [bh][chunk][ (g*4+dsub)*512 + (q4v*16+l15)*8 + half*4+rg ]
//      value V(kv=chunk*64+g*32+half*16+q4v*4+rg, d=dsub*16+l15) (PV B-frag order)
__global__ __launch_bounds__(256, 2) void proj_gemm_kernel(
    const unsigned short* __restrict__ Aq, const unsigned short* __restrict__ Akv,
    const unsigned short* __restrict__ W0, const unsigned short* __restrict__ W1,
    const unsigned short* __restrict__ W2,
    const float* __restrict__ bq, const float* __restrict__ bk, const float* __restrict__ bv,
    unsigned short* __restrict__ Oq, unsigned short* __restrict__ Ok,
    unsigned short* __restrict__ Ov) {
  __shared__ short As[128 * 32];
  __shared__ short Bs[128 * 32];
  const int z = blockIdx.z;
  const unsigned short* A = (z == 0) ? Aq : Akv;
  const unsigned short* Bt = (z == 0) ? W0 : (z == 1 ? W1 : W2);
  const float* bias = (z == 0) ? bq : (z == 1 ? bk : bv);
  unsigned short* out = (z == 0) ? Oq : (z == 1 ? Ok : Ov);
  const float oscale = (z == 0) ? QSCALE : 1.0f;

  const int tid = threadIdx.x;
  const int wave = tid >> 6, lane = tid & 63;
  const int l15 = lane & 15, q4 = lane >> 4;
  const int wm = wave >> 1, wn = wave & 1;
  const int m0 = blockIdx.y * 128, n0 = blockIdx.x * 128;

  f32x4 acc[4][4];
#pragma unroll
  for (int i = 0; i < 4; i++)
#pragma unroll
    for (int j = 0; j < 4; j++) acc[i][j] = (f32x4){0.f, 0.f, 0.f, 0.f};

  const int r = tid >> 2;
  const int c = (tid & 3) * 8;
  const unsigned short* gA0 = A + (size_t)(m0 + r) * EMB + c;
  const unsigned short* gA1 = A + (size_t)(m0 + r + 64) * EMB + c;
  const unsigned short* gB0 = Bt + (size_t)(n0 + r) * EMB + c;
  const unsigned short* gB1 = Bt + (size_t)(n0 + r + 64) * EMB + c;
  short* lA0 = As + tid * 8;
  short* lA1 = As + tid * 8 + 2048;
  short* lB0 = Bs + tid * 8;
  short* lB1 = Bs + tid * 8 + 2048;

  for (int kt = 0; kt < EMB / 32; kt++) {
    __syncthreads();
    gld16(gA0 + kt * 32, lA0);
    gld16(gA1 + kt * 32, lA1);
    gld16(gB0 + kt * 32, lB0);
    gld16(gB1 + kt * 32, lB1);
    __syncthreads();
    bf16x8 a[4], b[4];
#pragma unroll
    for (int i = 0; i < 4; i++)
      a[i] = *(const bf16x8*)(As + (wm * 64 + i * 16 + l15) * 32 + q4 * 8);
#pragma unroll
    for (int j = 0; j < 4; j++)
      b[j] = *(const bf16x8*)(Bs + (wn * 64 + j * 16 + l15) * 32 + q4 * 8);
#pragma unroll
    for (int i = 0; i < 4; i++)
#pragma unroll
      for (int j = 0; j < 4; j++)
        acc[i][j] = __builtin_amdgcn_mfma_f32_16x16x32_bf16(a[i], b[j], acc[i][j], 0, 0, 0);
  }

#pragma unroll
  for (int i = 0; i < 4; i++) {
    const int mrow = m0 + wm * 64 + i * 16 + q4 * 4;
#pragma unroll
    for (int j = 0; j < 4; j++) {
      const int n = n0 + wn * 64 + j * 16 + l15;
      const float bvv = bias[n];
      const int h = n >> 6, d = n & 63;
      const int bb = mrow >> 11, sq = mrow & 2047;
      if (z == 0) {
#pragma unroll
        for (int rg = 0; rg < 4; rg++)
          out[(size_t)((bb * NH + h) * SQL + sq + rg) * DH + d] =
              f2bf((acc[i][j][rg] + bvv) * oscale);
      } else if (z == 1) {
        const int chunk = sq >> 6, subK = (sq >> 4) & 3, l15k = sq & 15;
        const int halfd = d >> 5, q4k = (d >> 3) & 3, jk = d & 7;
        unsigned short* base = out + (size_t)(bb * NH + h) * (SKL * DH) + chunk * 4096 +
                               (subK * 2 + halfd) * 512 + (q4k * 16 + l15k) * 8 + jk;
#pragma unroll
        for (int rg = 0; rg < 4; rg++) base[rg * 8] = f2bf(acc[i][j][rg] + bvv);
      } else {
        const int chunk = sq >> 6, g = (sq >> 5) & 1, half = (sq >> 4) & 1, q4v = (sq >> 2) & 3;
        const int dsub = d >> 4, l15b = d & 15;
        ushort4 pk;
        pk.x = f2bf(acc[i][j][0] + bvv);
        pk.y = f2bf(acc[i][j][1] + bvv);
        pk.z = f2bf(acc[i][j][2] + bvv);
        pk.w = f2bf(acc[i][j][3] + bvv);
        *(ushort4*)(out + (size_t)(bb * NH + h) * (SKL * DH) + chunk * 4096 +
                    (g * 4 + dsub) * 512 + (q4v * 16 + l15b) * 8 + half * 4) = pk;
      }
    }
  }
}

// ---------------- fused flash attention v4 ----------------
// grid (16 qtiles, 64 bh), 256 threads; wave handles 32 q rows (ga=0,1).
// K and V both staged fragment-major in LDS (identity gld16), read as
// lane-contiguous ds_read_b128 — conflict-free by construction.
// S^T = K.Q^T; P stays in regs; PV = 16x16x32 with kv-permuted V frags.
__global__ __launch_bounds__(256, 3) void attn_kernel(
    const unsigned short* __restrict__ Qb,  // [64][2048][64] bf16 (pre-scaled)
    const unsigned short* __restrict__ Kf,  // [64][32][4096] frag-major
    const unsigned short* __restrict__ Vf,  // [64][32][4096] frag-major
    const unsigned int* __restrict__ mw,    // [8192 rows][32 chunks][32 words]
    float* __restrict__ out) {              // [4][2048][1024]
  __shared__ short Ls[2 * 8192];  // [buf][K 4096 | V 4096]
  const int tid = threadIdx.x;
  const int wave = tid >> 6, lane = tid & 63;
  const int l15 = lane & 15, q4 = lane >> 4;
  const int bh = blockIdx.y, b = bh >> 4, h = bh & 15;
  const int q0 = blockIdx.x * 128 + wave * 32;

  // Q b-frags for two 16-row groups
  bf16x8 qa0[2], qa1[2];
#pragma unroll
  for (int ga = 0; ga < 2; ga++) {
    const unsigned short* qg = Qb + (size_t)(bh * SQL + q0 + ga * 16 + l15) * DH + q4 * 8;
    qa0[ga] = *(const bf16x8*)qg;
    qa1[ga] = *(const bf16x8*)(qg + 32);
  }

  f32x4 o[2][4], osum[2];
#pragma unroll
  for (int ga = 0; ga < 2; ga++) {
    osum[ga] = (f32x4){0.f, 0.f, 0.f, 0.f};
#pragma unroll
    for (int d = 0; d < 4; d++) o[ga][d] = (f32x4){0.f, 0.f, 0.f, 0.f};
  }
  uint4 onesu = {0x3f803f80u, 0x3f803f80u, 0x3f803f80u, 0x3f803f80u};
  const bf16x8 ones8 = __builtin_bit_cast(bf16x8, onesu);

  const unsigned short* kg = Kf + (size_t)bh * (SKL * DH);
  const unsigned short* vg = Vf + (size_t)bh * (SKL * DH);
  const unsigned int* mq[2];
#pragma unroll
  for (int ga = 0; ga < 2; ga++)
    mq[ga] = mw + (size_t)(b * SQL + q0 + ga * 16 + l15) * 1024 + q4 * 8;

  // stage chunk 0 into buf 0
  gld16(kg + tid * 8, Ls + tid * 8);
  gld16(kg + 2048 + tid * 8, Ls + 2048 + tid * 8);
  gld16(vg + tid * 8, Ls + 4096 + tid * 8);
  gld16(vg + 2048 + tid * 8, Ls + 6144 + tid * 8);
  __syncthreads();

  for (int cch = 0; cch < 32; cch++) {
    const int buf = cch & 1;
    // mask loads FIRST (so waiting on them doesn't drain the prefetch)
    uint4 mA[2], mB[2];
#pragma unroll
    for (int ga = 0; ga < 2; ga++) {
      const unsigned int* mp = mq[ga] + cch * 32;
      mA[ga] = *(const uint4*)mp;       // subs 0,1 (g=0)
      mB[ga] = *(const uint4*)(mp + 4); // subs 2,3 (g=1)
    }
    if (cch < 31) {
      const unsigned short* ks = kg + (size_t)(cch + 1) * 4096;
      const unsigned short* vs = vg + (size_t)(cch + 1) * 4096;
      short* db = Ls + (buf ^ 1) * 8192;
      gld16(ks + tid * 8, db + tid * 8);
      gld16(ks + 2048 + tid * 8, db + 2048 + tid * 8);
      gld16(vs + tid * 8, db + 4096 + tid * 8);
      gld16(vs + 2048 + tid * 8, db + 6144 + tid * 8);
    }

    const short* Kls = Ls + buf * 8192;
    const short* Vls = Kls + 4096;

#pragma unroll
    for (int g = 0; g < 2; g++) {
      uint2 pp[2][2];  // [ga][si]
#pragma unroll
      for (int si = 0; si < 2; si++) {
        const int sub = g * 2 + si;
        bf16x8 afA = *(const bf16x8*)(Kls + sub * 1024 + lane * 8);
        bf16x8 afB = *(const bf16x8*)(Kls + sub * 1024 + 512 + lane * 8);
#pragma unroll
        for (int ga = 0; ga < 2; ga++) {
          f32x4 s4 = (f32x4){0.f, 0.f, 0.f, 0.f};
          s4 = __builtin_amdgcn_mfma_f32_16x16x32_bf16(afA, qa0[ga], s4, 0, 0, 0);
          s4 = __builtin_amdgcn_mfma_f32_16x16x32_bf16(afB, qa1[ga], s4, 0, 0, 0);
          const uint4 msk = g ? mB[ga] : mA[ga];
          const unsigned int wlo = si ? msk.z : msk.x;
          const unsigned int whi = si ? msk.w : msk.y;
          union { float f; uint32_t u; } e0, e1, e2, e3;
          e0.f = __builtin_exp2f(s4[0]);
          e1.f = __builtin_exp2f(s4[1]);
          e2.f = __builtin_exp2f(s4[2]);
          e3.f = __builtin_exp2f(s4[3]);
          pp[ga][si].x = (((e0.u + 0x8000u) >> 16) | ((e1.u + 0x8000u) & 0xffff0000u)) & wlo;
          pp[ga][si].y = (((e2.u + 0x8000u) >> 16) | ((e3.u + 0x8000u) & 0xffff0000u)) & whi;
        }
      }
      bf16x8 A8[2];
#pragma unroll
      for (int ga = 0; ga < 2; ga++) {
        uint4 au = {pp[ga][0].x, pp[ga][0].y, pp[ga][1].x, pp[ga][1].y};
        A8[ga] = __builtin_bit_cast(bf16x8, au);
      }
      bf16x8 vf[4];
#pragma unroll
      for (int dsub = 0; dsub < 4; dsub++)
        vf[dsub] = *(const bf16x8*)(Vls + (g * 4 + dsub) * 512 + lane * 8);
#pragma unroll
      for (int ga = 0; ga < 2; ga++) {
#pragma unroll
        for (int dsub = 0; dsub < 4; dsub++)
          o[ga][dsub] = __builtin_amdgcn_mfma_f32_16x16x32_bf16(A8[ga], vf[dsub], o[ga][dsub], 0, 0, 0);
        osum[ga] = __builtin_amdgcn_mfma_f32_16x16x32_bf16(A8[ga], ones8, osum[ga], 0, 0, 0);
      }
    }
    __syncthreads();
  }

#pragma unroll
  for (int ga = 0; ga < 2; ga++)
#pragma unroll
    for (int rg = 0; rg < 4; rg++) {
      const float inv = 1.0f / osum[ga][rg];
      float* op = out + (size_t)(b * SQL + q0 + ga * 16 + q4 * 4 + rg) * 1024 + h * DH + l15;
#pragma unroll
      for (int dsub = 0; dsub < 4; dsub++) op[dsub * 16] = o[ga][dsub][rg] * inv;
    }
}

extern "C" void kernel_launch(void* const* d_in, const int* in_sizes, int n_in,
                              void* d_out, int out_size, void* d_ws, size_t ws_size,
                              hipStream_t stream) {
  const float* x_q  = (const float*)d_in[0];
  const float* x_kv = (const float*)d_in[1];
  const int*   amask = (const int*)d_in[2];
  const float* w_q  = (const float*)d_in[3];
  const float* b_q  = (const float*)d_in[4];
  const float* w_k  = (const float*)d_in[5];
  const float* b_k  = (const float*)d_in[6];
  const float* w_v  = (const float*)d_in[7];
  const float* b_v  = (const float*)d_in[8];
  float* out = (float*)d_out;

  char* ws = (char*)d_ws;
  // Phase 1 (dead after proj)
  unsigned short* xq_bf  = (unsigned short*)(ws + 0);          // 16 MB
  unsigned short* xkv_bf = (unsigned short*)(ws + 16777216);   // 16 MB
  unsigned short* wqt    = (unsigned short*)(ws + 33554432);   // 2 MB
  unsigned short* wkt    = (unsigned short*)(ws + 35651584);   // 2 MB
  unsigned short* wvt    = (unsigned short*)(ws + 37748736);   // 2 MB
  // Phase 2 (live into attn)
  unsigned short* Qb     = (unsigned short*)(ws + 39845888);   // 16 MB
  unsigned short* Kfb    = (unsigned short*)(ws + 56623104);   // 16 MB
  unsigned short* Vfb    = (unsigned short*)(ws + 73400320);   // 16 MB
  // mask written AFTER proj, overlaying dead phase-1 region
  unsigned int*   M32    = (unsigned int*)(ws + 0);            // 32 MB

  cvt_bf16_kernel<<<8192, 256, 0, stream>>>(x_q, xq_bf, 2097152);
  cvt_bf16_kernel<<<8192, 256, 0, stream>>>(x_kv, xkv_bf, 2097152);
  wtrans_kernel<<<dim3(32, 32, 3), 256, 0, stream>>>(w_q, w_k, w_v, wqt, wkt, wvt);
  proj_gemm_kernel<<<dim3(8, 64, 3), 256, 0, stream>>>(
      xq_bf, xkv_bf, wqt, wkt, wvt, b_q, b_k, b_v, Qb, Kfb, Vfb);
  maskf_kernel<<<1024, 256, 0, stream>>>(amask, M32);
  attn_kernel<<<dim3(16, 64), 256, 0, stream>>>(Qb, Kfb, Vfb, M32, out);
}

// Round 7
// 347.496 us; speedup vs baseline: 1.9213x; 1.1129x over previous
//
#include <hip/hip_runtime.h>
#include <hip/hip_bf16.h>
#include <stdint.h>

#define BB 4
#define SQL 2048
#define SKL 2048
#define EMB 1024
#define NH 16
#define DH 64

typedef __bf16 bf16x8 __attribute__((ext_vector_type(8)));
typedef float f32x4 __attribute__((ext_vector_type(4)));

// scale folded into Q projection: 1/sqrt(64) * log2(e)
#define QSCALE 0.1803368801111144f

__device__ __forceinline__ unsigned short f2bf(float f) {
  union { float f; uint32_t u; } v; v.f = f;
  uint32_t u = v.u;
  return (unsigned short)((u + 0x7fffu + ((u >> 16) & 1u)) >> 16);
}

typedef const __attribute__((address_space(1))) void* gas_t;
typedef __attribute__((address_space(3))) void* las_t;
__device__ __forceinline__ void gld16(const void* g, void* l) {
  __builtin_amdgcn_global_load_lds((gas_t)g, (las_t)l, 16, 0, 0);
}

// ---------------- fp32 -> bf16 convert ----------------
__global__ void cvt_bf16_kernel(const float* __restrict__ src,
                                unsigned short* __restrict__ dst, int n4) {
  int i = blockIdx.x * 256 + threadIdx.x;
  if (i >= n4) return;
  float4 v = ((const float4*)src)[i];
  ushort4 o;
  o.x = f2bf(v.x); o.y = f2bf(v.y); o.z = f2bf(v.z); o.w = f2bf(v.w);
  ((ushort4*)dst)[i] = o;
}

// ---------------- w [K][N] fp32 -> w^T [N][K] bf16 ----------------
__global__ void wtrans_kernel(const float* __restrict__ w0, const float* __restrict__ w1,
                              const float* __restrict__ w2,
                              unsigned short* __restrict__ o0, unsigned short* __restrict__ o1,
                              unsigned short* __restrict__ o2) {
  __shared__ float t[32][33];
  const float* w = blockIdx.z == 0 ? w0 : (blockIdx.z == 1 ? w1 : w2);
  unsigned short* o = blockIdx.z == 0 ? o0 : (blockIdx.z == 1 ? o1 : o2);
  int tx = threadIdx.x & 31, ty = threadIdx.x >> 5;
  int n0 = blockIdx.x * 32, k0 = blockIdx.y * 32;
#pragma unroll
  for (int r = 0; r < 4; r++)
    t[ty + r * 8][tx] = w[(size_t)(k0 + ty + r * 8) * EMB + n0 + tx];
  __syncthreads();
#pragma unroll
  for (int r = 0; r < 4; r++)
    o[(size_t)(n0 + ty + r * 8) * EMB + k0 + tx] = f2bf(t[tx][ty + r * 8]);
}

// ---------------- mask -> permuted halfword AND-masks (coalesced) ----------------
// Layout: [row][chunk(32)][32 words]; word idx = q4*8 + sub*2 + pair holds
// kv = chunk*64 + sub*16 + q4*4 + pair*2 (lo) / +1 (hi); true -> 0x0000.
// One word per thread: 8B load (4-line wave footprint), 4B coalesced store.
__global__ void maskf_kernel(const int* __restrict__ m, unsigned int* __restrict__ w) {
  unsigned int W = blockIdx.x * 256 + threadIdx.x;  // 8192*1024 words
  unsigned int row = W >> 10;
  unsigned int chunk = (W >> 5) & 31;
  unsigned int idx = W & 31;
  unsigned int q4 = idx >> 3, sub = (idx >> 1) & 3, pair = idx & 1;
  unsigned int kv = chunk * 64 + sub * 16 + q4 * 4 + pair * 2;
  int2 mm = *(const int2*)(m + (size_t)row * 2048 + kv);
  w[W] = (mm.x ? 0u : 0xffffu) | (mm.y ? 0u : 0xffff0000u);
}

// ---------------- fused projection GEMMs (z = 0:Q, 1:K, 2:V) ----------------
// z 0: out[bh][s][64] bf16, pre-scaled by QSCALE.
// z 1: K fragment-major (QK^T A-frag order), z 2: V fragment-major (PV B-frag order).
__global__ __launch_bounds__(256, 2) void proj_gemm_kernel(
    const unsigned short* __restrict__ Aq, const unsigned short* __restrict__ Akv,
    const unsigned short* __restrict__ W0, const unsigned short* __restrict__ W1,
    const unsigned short* __restrict__ W2,
    const float* __restrict__ bq, const float* __restrict__ bk, const float* __restrict__ bv,
    unsigned short* __restrict__ Oq, unsigned short* __restrict__ Ok,
    unsigned short* __restrict__ Ov) {
  __shared__ short As[128 * 32];
  __shared__ short Bs[128 * 32];
  const int z = blockIdx.z;
  const unsigned short* A = (z == 0) ? Aq : Akv;
  const unsigned short* Bt = (z == 0) ? W0 : (z == 1 ? W1 : W2);
  const float* bias = (z == 0) ? bq : (z == 1 ? bk : bv);
  unsigned short* out = (z == 0) ? Oq : (z == 1 ? Ok : Ov);
  const float oscale = (z == 0) ? QSCALE : 1.0f;

  const int tid = threadIdx.x;
  const int wave = tid >> 6, lane = tid & 63;
  const int l15 = lane & 15, q4 = lane >> 4;
  const int wm = wave >> 1, wn = wave & 1;
  const int m0 = blockIdx.y * 128, n0 = blockIdx.x * 128;

  f32x4 acc[4][4];
#pragma unroll
  for (int i = 0; i < 4; i++)
#pragma unroll
    for (int j = 0; j < 4; j++) acc[i][j] = (f32x4){0.f, 0.f, 0.f, 0.f};

  const int r = tid >> 2;
  const int c = (tid & 3) * 8;
  const unsigned short* gA0 = A + (size_t)(m0 + r) * EMB + c;
  const unsigned short* gA1 = A + (size_t)(m0 + r + 64) * EMB + c;
  const unsigned short* gB0 = Bt + (size_t)(n0 + r) * EMB + c;
  const unsigned short* gB1 = Bt + (size_t)(n0 + r + 64) * EMB + c;
  short* lA0 = As + tid * 8;
  short* lA1 = As + tid * 8 + 2048;
  short* lB0 = Bs + tid * 8;
  short* lB1 = Bs + tid * 8 + 2048;

  for (int kt = 0; kt < EMB / 32; kt++) {
    __syncthreads();
    gld16(gA0 + kt * 32, lA0);
    gld16(gA1 + kt * 32, lA1);
    gld16(gB0 + kt * 32, lB0);
    gld16(gB1 + kt * 32, lB1);
    __syncthreads();
    bf16x8 a[4], b[4];
#pragma unroll
    for (int i = 0; i < 4; i++)
      a[i] = *(const bf16x8*)(As + (wm * 64 + i * 16 + l15) * 32 + q4 * 8);
#pragma unroll
    for (int j = 0; j < 4; j++)
      b[j] = *(const bf16x8*)(Bs + (wn * 64 + j * 16 + l15) * 32 + q4 * 8);
#pragma unroll
    for (int i = 0; i < 4; i++)
#pragma unroll
      for (int j = 0; j < 4; j++)
        acc[i][j] = __builtin_amdgcn_mfma_f32_16x16x32_bf16(a[i], b[j], acc[i][j], 0, 0, 0);
  }

#pragma unroll
  for (int i = 0; i < 4; i++) {
    const int mrow = m0 + wm * 64 + i * 16 + q4 * 4;
#pragma unroll
    for (int j = 0; j < 4; j++) {
      const int n = n0 + wn * 64 + j * 16 + l15;
      const float bvv = bias[n];
      const int h = n >> 6, d = n & 63;
      const int bb = mrow >> 11, sq = mrow & 2047;
      if (z == 0) {
#pragma unroll
        for (int rg = 0; rg < 4; rg++)
          out[(size_t)((bb * NH + h) * SQL + sq + rg) * DH + d] =
              f2bf((acc[i][j][rg] + bvv) * oscale);
      } else if (z == 1) {
        const int chunk = sq >> 6, subK = (sq >> 4) & 3, l15k = sq & 15;
        const int halfd = d >> 5, q4k = (d >> 3) & 3, jk = d & 7;
        unsigned short* base = out + (size_t)(bb * NH + h) * (SKL * DH) + chunk * 4096 +
                               (subK * 2 + halfd) * 512 + (q4k * 16 + l15k) * 8 + jk;
#pragma unroll
        for (int rg = 0; rg < 4; rg++) base[rg * 8] = f2bf(acc[i][j][rg] + bvv);
      } else {
        const int chunk = sq >> 6, g = (sq >> 5) & 1, half = (sq >> 4) & 1, q4v = (sq >> 2) & 3;
        const int dsub = d >> 4, l15b = d & 15;
        ushort4 pk;
        pk.x = f2bf(acc[i][j][0] + bvv);
        pk.y = f2bf(acc[i][j][1] + bvv);
        pk.z = f2bf(acc[i][j][2] + bvv);
        pk.w = f2bf(acc[i][j][3] + bvv);
        *(ushort4*)(out + (size_t)(bb * NH + h) * (SKL * DH) + chunk * 4096 +
                    (g * 4 + dsub) * 512 + (q4v * 16 + l15b) * 8 + half * 4) = pk;
      }
    }
  }
}

// ---------------- fused flash attention v4.1 (raw v_exp) ----------------
__global__ __launch_bounds__(256, 3) void attn_kernel(
    const unsigned short* __restrict__ Qb,  // [64][2048][64] bf16 (pre-scaled)
    const unsigned short* __restrict__ Kf,  // [64][32][4096] frag-major
    const unsigned short* __restrict__ Vf,  // [64][32][4096] frag-major
    const unsigned int* __restrict__ mw,    // [8192 rows][32 chunks][32 words]
    float* __restrict__ out) {              // [4][2048][1024]
  __shared__ short Ls[2 * 8192];  // [buf][K 4096 | V 4096]
  const int tid = threadIdx.x;
  const int wave = tid >> 6, lane = tid & 63;
  const int l15 = lane & 15, q4 = lane >> 4;
  const int bh = blockIdx.y, b = bh >> 4, h = bh & 15;
  const int q0 = blockIdx.x * 128 + wave * 32;

  bf16x8 qa0[2], qa1[2];
#pragma unroll
  for (int ga = 0; ga < 2; ga++) {
    const unsigned short* qg = Qb + (size_t)(bh * SQL + q0 + ga * 16 + l15) * DH + q4 * 8;
    qa0[ga] = *(const bf16x8*)qg;
    qa1[ga] = *(const bf16x8*)(qg + 32);
  }

  f32x4 o[2][4], osum[2];
#pragma unroll
  for (int ga = 0; ga < 2; ga++) {
    osum[ga] = (f32x4){0.f, 0.f, 0.f, 0.f};
#pragma unroll
    for (int d = 0; d < 4; d++) o[ga][d] = (f32x4){0.f, 0.f, 0.f, 0.f};
  }
  uint4 onesu = {0x3f803f80u, 0x3f803f80u, 0x3f803f80u, 0x3f803f80u};
  const bf16x8 ones8 = __builtin_bit_cast(bf16x8, onesu);

  const unsigned short* kg = Kf + (size_t)bh * (SKL * DH);
  const unsigned short* vg = Vf + (size_t)bh * (SKL * DH);
  const unsigned int* mq[2];
#pragma unroll
  for (int ga = 0; ga < 2; ga++)
    mq[ga] = mw + (size_t)(b * SQL + q0 + ga * 16 + l15) * 1024 + q4 * 8;

  // stage chunk 0 into buf 0
  gld16(kg + tid * 8, Ls + tid * 8);
  gld16(kg + 2048 + tid * 8, Ls + 2048 + tid * 8);
  gld16(vg + tid * 8, Ls + 4096 + tid * 8);
  gld16(vg + 2048 + tid * 8, Ls + 6144 + tid * 8);
  __syncthreads();

  for (int cch = 0; cch < 32; cch++) {
    const int buf = cch & 1;
    // mask loads FIRST (so waiting on them doesn't drain the prefetch)
    uint4 mA[2], mB[2];
#pragma unroll
    for (int ga = 0; ga < 2; ga++) {
      const unsigned int* mp = mq[ga] + cch * 32;
      mA[ga] = *(const uint4*)mp;       // subs 0,1 (g=0)
      mB[ga] = *(const uint4*)(mp + 4); // subs 2,3 (g=1)
    }
    if (cch < 31) {
      const unsigned short* ks = kg + (size_t)(cch + 1) * 4096;
      const unsigned short* vs = vg + (size_t)(cch + 1) * 4096;
      short* db = Ls + (buf ^ 1) * 8192;
      gld16(ks + tid * 8, db + tid * 8);
      gld16(ks + 2048 + tid * 8, db + 2048 + tid * 8);
      gld16(vs + tid * 8, db + 4096 + tid * 8);
      gld16(vs + 2048 + tid * 8, db + 6144 + tid * 8);
    }

    const short* Kls = Ls + buf * 8192;
    const short* Vls = Kls + 4096;

#pragma unroll
    for (int g = 0; g < 2; g++) {
      uint2 pp[2][2];  // [ga][si]
#pragma unroll
      for (int si = 0; si < 2; si++) {
        const int sub = g * 2 + si;
        bf16x8 afA = *(const bf16x8*)(Kls + sub * 1024 + lane * 8);
        bf16x8 afB = *(const bf16x8*)(Kls + sub * 1024 + 512 + lane * 8);
#pragma unroll
        for (int ga = 0; ga < 2; ga++) {
          f32x4 s4 = (f32x4){0.f, 0.f, 0.f, 0.f};
          s4 = __builtin_amdgcn_mfma_f32_16x16x32_bf16(afA, qa0[ga], s4, 0, 0, 0);
          s4 = __builtin_amdgcn_mfma_f32_16x16x32_bf16(afB, qa1[ga], s4, 0, 0, 0);
          const uint4 msk = g ? mB[ga] : mA[ga];
          const unsigned int wlo = si ? msk.z : msk.x;
          const unsigned int whi = si ? msk.w : msk.y;
          union { float f; uint32_t u; } e0, e1, e2, e3;
          e0.f = __builtin_amdgcn_exp2f(s4[0]);
          e1.f = __builtin_amdgcn_exp2f(s4[1]);
          e2.f = __builtin_amdgcn_exp2f(s4[2]);
          e3.f = __builtin_amdgcn_exp2f(s4[3]);
          pp[ga][si].x = (((e0.u + 0x8000u) >> 16) | ((e1.u + 0x8000u) & 0xffff0000u)) & wlo;
          pp[ga][si].y = (((e2.u + 0x8000u) >> 16) | ((e3.u + 0x8000u) & 0xffff0000u)) & whi;
        }
      }
      bf16x8 A8[2];
#pragma unroll
      for (int ga = 0; ga < 2; ga++) {
        uint4 au = {pp[ga][0].x, pp[ga][0].y, pp[ga][1].x, pp[ga][1].y};
        A8[ga] = __builtin_bit_cast(bf16x8, au);
      }
      bf16x8 vf[4];
#pragma unroll
      for (int dsub = 0; dsub < 4; dsub++)
        vf[dsub] = *(const bf16x8*)(Vls + (g * 4 + dsub) * 512 + lane * 8);
#pragma unroll
      for (int ga = 0; ga < 2; ga++) {
#pragma unroll
        for (int dsub = 0; dsub < 4; dsub++)
          o[ga][dsub] = __builtin_amdgcn_mfma_f32_16x16x32_bf16(A8[ga], vf[dsub], o[ga][dsub], 0, 0, 0);
        osum[ga] = __builtin_amdgcn_mfma_f32_16x16x32_bf16(A8[ga], ones8, osum[ga], 0, 0, 0);
      }
    }
    __syncthreads();
  }

#pragma unroll
  for (int ga = 0; ga < 2; ga++)
#pragma unroll
    for (int rg = 0; rg < 4; rg++) {
      const float inv = 1.0f / osum[ga][rg];
      float* op = out + (size_t)(b * SQL + q0 + ga * 16 + q4 * 4 + rg) * 1024 + h * DH + l15;
#pragma unroll
      for (int dsub = 0; dsub < 4; dsub++) op[dsub * 16] = o[ga][dsub][rg] * inv;
    }
}

extern "C" void kernel_launch(void* const* d_in, const int* in_sizes, int n_in,
                              void* d_out, int out_size, void* d_ws, size_t ws_size,
                              hipStream_t stream) {
  const float* x_q  = (const float*)d_in[0];
  const float* x_kv = (const float*)d_in[1];
  const int*   amask = (const int*)d_in[2];
  const float* w_q  = (const float*)d_in[3];
  const float* b_q  = (const float*)d_in[4];
  const float* w_k  = (const float*)d_in[5];
  const float* b_k  = (const float*)d_in[6];
  const float* w_v  = (const float*)d_in[7];
  const float* b_v  = (const float*)d_in[8];
  float* out = (float*)d_out;

  char* ws = (char*)d_ws;
  // Phase 1 (dead after proj)
  unsigned short* xq_bf  = (unsigned short*)(ws + 0);          // 16 MB
  unsigned short* xkv_bf = (unsigned short*)(ws + 16777216);   // 16 MB
  unsigned short* wqt    = (unsigned short*)(ws + 33554432);   // 2 MB
  unsigned short* wkt    = (unsigned short*)(ws + 35651584);   // 2 MB
  unsigned short* wvt    = (unsigned short*)(ws + 37748736);   // 2 MB
  // Phase 2 (live into attn)
  unsigned short* Qb     = (unsigned short*)(ws + 39845888);   // 16 MB
  unsigned short* Kfb    = (unsigned short*)(ws + 56623104);   // 16 MB
  unsigned short* Vfb    = (unsigned short*)(ws + 73400320);   // 16 MB
  // mask written AFTER proj, overlaying dead phase-1 region
  unsigned int*   M32    = (unsigned int*)(ws + 0);            // 32 MB

  cvt_bf16_kernel<<<8192, 256, 0, stream>>>(x_q, xq_bf, 2097152);
  cvt_bf16_kernel<<<8192, 256, 0, stream>>>(x_kv, xkv_bf, 2097152);
  wtrans_kernel<<<dim3(32, 32, 3), 256, 0, stream>>>(w_q, w_k, w_v, wqt, wkt, wvt);
  proj_gemm_kernel<<<dim3(8, 64, 3), 256, 0, stream>>>(
      xq_bf, xkv_bf, wqt, wkt, wvt, b_q, b_k, b_v, Qb, Kfb, Vfb);
  maskf_kernel<<<32768, 256, 0, stream>>>(amask, M32);
  attn_kernel<<<dim3(16, 64), 256, 0, stream>>>(Qb, Kfb, Vfb, M32, out);
}